// Round 6
// baseline (4028.995 us; speedup 1.0000x reference)
//
#include <hip/hip_runtime.h>
#include <math.h>

#define NB 32
#define NT 128
#define ND 384
#define NH 6
#define NL 6
#define NV 32000
#define NHS 64
#define NBT (NB*NT)      // 4096
#define NFF (4*ND)       // 1536
#define NQKV (3*ND)      // 1152
#define LNEPS 1e-5f

typedef unsigned short u16;
typedef unsigned int   u32;
typedef __attribute__((ext_vector_type(8))) short bf16x8;
typedef __attribute__((ext_vector_type(4))) float f32x4;

#define FLAG_BIAS 1
#define FLAG_RELU 2
#define FLAG_RESID 4
#define FLAG_BF16OUT 8

__device__ __forceinline__ float bf2f(u16 h) { return __uint_as_float((u32)h << 16); }
__device__ __forceinline__ u16 f2bf(float f) {
    u32 u = __float_as_uint(f);
    u32 r = u + 0x7fffu + ((u >> 16) & 1u);
    return (u16)(r >> 16);
}

__device__ __forceinline__ float wave_sum(float v) {
#pragma unroll
    for (int m = 1; m < 64; m <<= 1) v += __shfl_xor(v, m, 64);
    return v;
}
__device__ __forceinline__ float wave_max(float v) {
#pragma unroll
    for (int m = 1; m < 64; m <<= 1) v = fmaxf(v, __shfl_xor(v, m, 64));
    return v;
}

// =================== device building blocks ===================

// LayerNorm: ONE WAVE per row, 6 elems/lane, no block barriers.
template <int BF16OUT>
__device__ __forceinline__ void dev_ln_rows(const float* __restrict__ x,
        const float* __restrict__ g, const float* __restrict__ be,
        float* __restrict__ outf, u16* __restrict__ outb, int row) {
    int lane = threadIdx.x & 63;
    const float* xr = x + (size_t)row * ND;
    float v[6];
    float s = 0.f;
#pragma unroll
    for (int i = 0; i < 6; i++) { v[i] = xr[lane * 6 + i]; s += v[i]; }
    s = wave_sum(s);
    float mean = s * (1.f / ND);
    float ss = 0.f;
#pragma unroll
    for (int i = 0; i < 6; i++) { v[i] -= mean; ss += v[i] * v[i]; }
    ss = wave_sum(ss);
    float rstd = rsqrtf(ss * (1.f / ND) + LNEPS);
    if (BF16OUT) {
        u16* orow = outb + (size_t)row * ND;
#pragma unroll
        for (int i = 0; i < 6; i++)
            orow[lane * 6 + i] = f2bf(v[i] * rstd * g[lane * 6 + i] + be[lane * 6 + i]);
    } else {
        float* orow = outf + (size_t)row * ND;
#pragma unroll
        for (int i = 0; i < 6; i++)
            orow[lane * 6 + i] = v[i] * rstd * g[lane * 6 + i] + be[lane * 6 + i];
    }
}

// bf16 MFMA GEMM tile: C[bm*128..][bn*128..] = A[M,K] @ Bt[N,K]^T (+bias/relu/resid)
#define BM 128
#define BN 128
#define BK 32
#define KPAD 40

__device__ __forceinline__ void dev_gemm_tile(
    const u16* __restrict__ A, const u16* __restrict__ Bt,
    const float* __restrict__ bias, float* __restrict__ Cf, u16* __restrict__ Cb,
    int N, int K, int bm, int bn, int flags, u16* As, u16* Bs)
{
    int tid = threadIdx.x;
    int row0 = bm * BM, col0 = bn * BN;
    int wave = tid >> 6, lane = tid & 63;
    int wr = wave >> 1, wc = wave & 1;
    int lrow = lane & 15;
    int kgrp = lane >> 4;

    f32x4 acc[4][4];
#pragma unroll
    for (int i = 0; i < 4; i++)
#pragma unroll
        for (int j = 0; j < 4; j++) acc[i][j] = (f32x4){0.f, 0.f, 0.f, 0.f};

    int c0 = tid * 2;
    int sr0 = c0 >> 2, sk0 = (c0 & 3) * 8;
    int c1 = c0 + 1;
    int sr1 = c1 >> 2, sk1 = (c1 & 3) * 8;
    const size_t arow0 = (size_t)(row0 + sr0) * K;
    const size_t arow1 = (size_t)(row0 + sr1) * K;
    const size_t brow0 = (size_t)(col0 + sr0) * K;
    const size_t brow1 = (size_t)(col0 + sr1) * K;

    for (int k0 = 0; k0 < K; k0 += BK) {
        bf16x8 a0 = *(const bf16x8*)&A[arow0 + k0 + sk0];
        bf16x8 a1 = *(const bf16x8*)&A[arow1 + k0 + sk1];
        bf16x8 b0 = *(const bf16x8*)&Bt[brow0 + k0 + sk0];
        bf16x8 b1 = *(const bf16x8*)&Bt[brow1 + k0 + sk1];
        __syncthreads();   // prior reads of As/Bs (or prior-stage smem use) done
        *(bf16x8*)&As[sr0 * KPAD + sk0] = a0;
        *(bf16x8*)&As[sr1 * KPAD + sk1] = a1;
        *(bf16x8*)&Bs[sr0 * KPAD + sk0] = b0;
        *(bf16x8*)&Bs[sr1 * KPAD + sk1] = b1;
        __syncthreads();

        bf16x8 af[4], bfr[4];
#pragma unroll
        for (int mi = 0; mi < 4; mi++)
            af[mi] = *(const bf16x8*)&As[(wr * 64 + mi * 16 + lrow) * KPAD + kgrp * 8];
#pragma unroll
        for (int ni = 0; ni < 4; ni++)
            bfr[ni] = *(const bf16x8*)&Bs[(wc * 64 + ni * 16 + lrow) * KPAD + kgrp * 8];
#pragma unroll
        for (int mi = 0; mi < 4; mi++)
#pragma unroll
            for (int ni = 0; ni < 4; ni++)
                acc[mi][ni] = __builtin_amdgcn_mfma_f32_16x16x32_bf16(
                    af[mi], bfr[ni], acc[mi][ni], 0, 0, 0);
    }
#pragma unroll
    for (int mi = 0; mi < 4; mi++) {
#pragma unroll
        for (int ni = 0; ni < 4; ni++) {
            int c = col0 + wc * 64 + ni * 16 + lrow;
            int rb = row0 + wr * 64 + mi * 16 + kgrp * 4;
#pragma unroll
            for (int j = 0; j < 4; j++) {
                size_t idx = (size_t)(rb + j) * N + c;
                float v = acc[mi][ni][j];
                if (flags & FLAG_BIAS) v += bias[c];
                if (flags & FLAG_RELU) v = fmaxf(v, 0.f);
                if (flags & FLAG_RESID) v += Cf[idx];
                if (flags & FLAG_BF16OUT) Cb[idx] = f2bf(v);
                else Cf[idx] = v;
            }
        }
    }
}

// attention for one (b,h): 256 threads; tid<128 each own a query row
__device__ __forceinline__ void dev_attn(const u16* __restrict__ qkv,
                                         u16* __restrict__ o, int bh,
                                         float* ks, float* vs) {
    __syncthreads();          // guard smem reuse from previous stage
    int b = bh / NH, h = bh % NH;
    int tid = threadIdx.x;
    size_t row0 = (size_t)b * NT;

    for (int i = tid; i < NT * (NHS / 8); i += 256) {
        int r = i >> 3, c8 = (i & 7) * 8;
        bf16x8 kv = *(const bf16x8*)&qkv[(row0 + r) * NQKV + ND + h * NHS + c8];
        bf16x8 vv = *(const bf16x8*)&qkv[(row0 + r) * NQKV + 2 * ND + h * NHS + c8];
#pragma unroll
        for (int j = 0; j < 8; j++) {
            ks[r * NHS + c8 + j] = bf2f((u16)kv[j]);
            vs[r * NHS + c8 + j] = bf2f((u16)vv[j]);
        }
    }
    float qr[NHS];
    if (tid < NT) {
        const u16* qp = &qkv[(row0 + tid) * NQKV + h * NHS];
#pragma unroll
        for (int e8 = 0; e8 < 8; e8++) {
            bf16x8 qv = *(const bf16x8*)(qp + e8 * 8);
#pragma unroll
            for (int j = 0; j < 8; j++) qr[e8 * 8 + j] = bf2f((u16)qv[j]);
        }
    }
    __syncthreads();
    if (tid < NT) {
        const float scale = 0.125f;
        float m = -1e30f;
        for (int j = 0; j <= tid; ++j) {
            float dot = 0.f;
#pragma unroll
            for (int e = 0; e < NHS; e++) dot += qr[e] * ks[j * NHS + e];
            m = fmaxf(m, dot * scale);
        }
        float acc[NHS];
#pragma unroll
        for (int e = 0; e < NHS; e++) acc[e] = 0.f;
        float s = 0.f;
        for (int j = 0; j <= tid; ++j) {
            float dot = 0.f;
#pragma unroll
            for (int e = 0; e < NHS; e++) dot += qr[e] * ks[j * NHS + e];
            float p = __expf(dot * scale - m);
            s += p;
#pragma unroll
            for (int e = 0; e < NHS; e++) acc[e] += p * vs[j * NHS + e];
        }
        float inv = 1.f / s;
        u16* op = o + (row0 + tid) * ND + h * NHS;
#pragma unroll
        for (int e = 0; e < NHS; e++) op[e] = f2bf(acc[e] * inv);
    }
}

// 32x32 transpose tile + fp32->bf16
__device__ __forceinline__ void dev_transpose(const float* __restrict__ in,
        u16* __restrict__ out, int R, int C, long izs, long ozs, int zH, long ohs,
        int z, int r0, int c0, float (*tile)[33]) {
    long in_off = (long)z * izs;
    long out_off;
    if (zH > 1) { int l = z / zH, h = z % zH; out_off = (long)l * ozs + (long)h * ohs; }
    else out_off = (long)z * ozs;
    int tx = threadIdx.x & 31, ty = threadIdx.x >> 5;
#pragma unroll
    for (int i = 0; i < 32; i += 8)
        tile[ty + i][tx] = in[in_off + (size_t)(r0 + ty + i) * C + c0 + tx];
    __syncthreads();
#pragma unroll
    for (int i = 0; i < 32; i += 8)
        out[out_off + (size_t)(c0 + ty + i) * R + r0 + tx] = f2bf(tile[tx][ty + i]);
}

// =================== standalone wrappers (fallback paths + logits) ===================

__global__ void embed_kernel(const int* __restrict__ tokens,
                             const float* __restrict__ te,
                             const float* __restrict__ pe,
                             float* __restrict__ x) {
    int i = blockIdx.x * 256 + threadIdx.x;
    if (i >= NBT * ND) return;
    int d = i % ND, bt = i / ND, t = bt % NT;
    x[i] = te[(size_t)tokens[bt] * ND + d] + pe[t * ND + d];
}

__global__ __launch_bounds__(256) void transpose_cvt_kernel(
    const float* __restrict__ in, u16* __restrict__ out,
    int R, int C, long izs, long ozs, int zH, long ohs) {
    __shared__ float tile[32][33];
    dev_transpose(in, out, R, C, izs, ozs, zH, ohs,
                  blockIdx.z, blockIdx.y * 32, blockIdx.x * 32, tile);
}

template <int BF16OUT>
__global__ __launch_bounds__(256) void ln_kernel(const float* __restrict__ x,
        const float* __restrict__ g, const float* __restrict__ be,
        float* __restrict__ outf, u16* __restrict__ outb) {
    int r = blockIdx.x * 4 + (threadIdx.x >> 6);
    dev_ln_rows<BF16OUT>(x, g, be, outf, outb, r);
}

__global__ __launch_bounds__(256) void gemm_bf16_kernel(
    const u16* __restrict__ A, const u16* __restrict__ Bt,
    const float* __restrict__ bias, float* __restrict__ Cf, u16* __restrict__ Cb,
    int N, int K, int flags) {
    __shared__ u16 As[BM * KPAD];
    __shared__ u16 Bs[BN * KPAD];
    dev_gemm_tile(A, Bt, bias, Cf, Cb, N, K, blockIdx.y, blockIdx.x, flags, As, Bs);
}

__global__ __launch_bounds__(256) void attn_kernel(const u16* __restrict__ qkv,
                                                   u16* __restrict__ o) {
    __shared__ float ks[NT * NHS];
    __shared__ float vs[NT * NHS];
    dev_attn(qkv, o, blockIdx.x, ks, vs);
}

__global__ __launch_bounds__(256) void gemm_f32_kernel(const float* __restrict__ A,
        const float* __restrict__ Bm, const float* __restrict__ bias,
        float* __restrict__ C, int M, int N, int K, int flags) {
    __shared__ float Asl[16][65];
    __shared__ float Bsl[16][64];
    int bn = blockIdx.x, bm = blockIdx.y;
    int tid = threadIdx.x;
    int tr = tid >> 4, tc = tid & 15;
    int row0 = bm * 64, col0 = bn * 64;
    float acc[4][4];
#pragma unroll
    for (int i = 0; i < 4; i++)
#pragma unroll
        for (int j = 0; j < 4; j++) acc[i][j] = 0.f;
    for (int k0 = 0; k0 < K; k0 += 16) {
#pragma unroll
        for (int i = tid; i < 1024; i += 256) {
            int r = i >> 4, c = i & 15;
            Asl[c][r] = A[(size_t)(row0 + r) * K + (k0 + c)];
        }
#pragma unroll
        for (int i = tid; i < 1024; i += 256) {
            int r = i >> 6, c = i & 63;
            Bsl[r][c] = Bm[(size_t)(k0 + r) * N + (col0 + c)];
        }
        __syncthreads();
#pragma unroll
        for (int kk = 0; kk < 16; kk++) {
            float a[4], bv[4];
#pragma unroll
            for (int i = 0; i < 4; i++) a[i] = Asl[kk][tr * 4 + i];
#pragma unroll
            for (int j = 0; j < 4; j++) bv[j] = Bsl[kk][tc * 4 + j];
#pragma unroll
            for (int i = 0; i < 4; i++)
#pragma unroll
                for (int j = 0; j < 4; j++) acc[i][j] += a[i] * bv[j];
        }
        __syncthreads();
    }
#pragma unroll
    for (int i = 0; i < 4; i++) {
        size_t r = (size_t)row0 + tr * 4 + i;
#pragma unroll
        for (int j = 0; j < 4; j++) {
            int cc = col0 + tc * 4 + j;
            float t = acc[i][j];
            if (flags & 1) t += bias[cc];
            C[r * (size_t)N + cc] = t;
        }
    }
}

__global__ __launch_bounds__(1024) void softmax_kernel(float* __restrict__ out) {
    __shared__ float red[16];
    int row = blockIdx.x, tid = threadIdx.x;
    float* p = out + (size_t)row * NV;
    const int nch = NV / 4;
    float4 v[8];
    float m = -1e30f;
#pragma unroll
    for (int i = 0; i < 8; i++) {
        int c = tid + i * 1024;
        if (c < nch) {
            v[i] = ((const float4*)p)[c];
            m = fmaxf(m, fmaxf(fmaxf(v[i].x, v[i].y), fmaxf(v[i].z, v[i].w)));
        }
    }
    m = wave_max(m);
    if ((tid & 63) == 0) red[tid >> 6] = m;
    __syncthreads();
    float mm = red[0];
#pragma unroll
    for (int i = 1; i < 16; i++) mm = fmaxf(mm, red[i]);
    __syncthreads();
    float s = 0.f;
#pragma unroll
    for (int i = 0; i < 8; i++) {
        int c = tid + i * 1024;
        if (c < nch) {
            v[i].x = __expf(v[i].x - mm); v[i].y = __expf(v[i].y - mm);
            v[i].z = __expf(v[i].z - mm); v[i].w = __expf(v[i].w - mm);
            s += v[i].x + v[i].y + v[i].z + v[i].w;
        }
    }
    s = wave_sum(s);
    if ((tid & 63) == 0) red[tid >> 6] = s;
    __syncthreads();
    float ss = 0.f;
#pragma unroll
    for (int i = 0; i < 16; i++) ss += red[i];
    float inv = 1.f / ss;
#pragma unroll
    for (int i = 0; i < 8; i++) {
        int c = tid + i * 1024;
        if (c < nch) {
            v[i].x *= inv; v[i].y *= inv; v[i].z *= inv; v[i].w *= inv;
            ((float4*)p)[c] = v[i];
        }
    }
}

// =================== fused prep: all transposes + embedding ===================

#define PREP_GRID 28512

__global__ __launch_bounds__(256) void prep_kernel(
    const int* __restrict__ tokens, const float* __restrict__ te,
    const float* __restrict__ pe, float* __restrict__ xbuf,
    const float* __restrict__ Wq, const float* __restrict__ Wk,
    const float* __restrict__ Wv, const float* __restrict__ Wo,
    const float* __restrict__ W1, const float* __restrict__ W2,
    const float* __restrict__ Wout,
    u16* __restrict__ wqkvt, u16* __restrict__ wot, u16* __restrict__ w1t,
    u16* __restrict__ w2t, u16* __restrict__ woutt)
{
    __shared__ float tile[32][33];
    int bid = blockIdx.x, tid = threadIdx.x;
    const int nE = (NBT * ND) / 256;                 // 6144
    const int nQ = NL * NH * (ND / 32) * (NHS / 32); // 864
    const int nWo = NL * (ND / 32) * (ND / 32);      // 864
    const int nW1 = NL * (ND / 32) * (NFF / 32);     // 3456
    const int nW2 = NL * (NFF / 32) * (ND / 32);     // 3456
    const int s0 = nE, s3 = s0 + 3 * nQ, s4 = s3 + nWo, s5 = s4 + nW1, s6 = s5 + nW2;

    if (bid < s0) {
        int i = bid * 256 + tid;
        int d = i % ND, bt = i / ND, t = bt % NT;
        xbuf[i] = te[(size_t)tokens[bt] * ND + d] + pe[t * ND + d];
        return;
    }
    const float* in; u16* out; int R, C, zH; long izs, ozs, ohs; int local;
    if (bid < s3) {
        int w = (bid - s0) / nQ;
        local = (bid - s0) % nQ;
        in = (w == 0) ? Wq : (w == 1) ? Wk : Wv;
        out = wqkvt + (size_t)w * ND * ND;   // shift by w*384 rows within [NQKV][ND]
        R = ND; C = NHS; izs = (long)ND * NHS; ozs = (long)NQKV * ND; zH = NH; ohs = (long)NHS * ND;
    } else if (bid < s4) {
        local = bid - s3; in = Wo; out = wot;
        R = ND; C = ND; izs = (long)ND * ND; ozs = (long)ND * ND; zH = 1; ohs = 0;
    } else if (bid < s5) {
        local = bid - s4; in = W1; out = w1t;
        R = ND; C = NFF; izs = (long)ND * NFF; ozs = (long)NFF * ND; zH = 1; ohs = 0;
    } else if (bid < s6) {
        local = bid - s5; in = W2; out = w2t;
        R = NFF; C = ND; izs = (long)NFF * ND; ozs = (long)ND * NFF; zH = 1; ohs = 0;
    } else {
        local = bid - s6; in = Wout; out = woutt;
        R = ND; C = NV; izs = 0; ozs = 0; zH = 1; ohs = 0;
    }
    int tC = C / 32, tR = R / 32, perz = tR * tC;
    int z = local / perz, rem = local % perz;
    int rt = rem / tC, ct = rem % tC;
    dev_transpose(in, out, R, C, izs, ozs, zH, ohs, z, rt * 32, ct * 32, tile);
}

// =================== mega kernel: 6 layers + final LN, grid-barriered ===================

__device__ __forceinline__ void gsync(unsigned* bar, unsigned gen_target, int nblk) {
    __syncthreads();
    if (threadIdx.x == 0) {
        __threadfence();   // release: make this block's writes device-visible
        if (atomicAdd(&bar[0], 1u) == (unsigned)nblk - 1u) {
            atomicExch(&bar[0], 0u);
            __threadfence();
            atomicAdd(&bar[1], 1u);
        } else {
            long spin = 0;
            while (atomicAdd(&bar[1], 0u) < gen_target) {
                __builtin_amdgcn_s_sleep(8);
                if (++spin > 10000000L) break;   // fail loud (absmax), never hang
            }
        }
    }
    __syncthreads();
    __threadfence();       // acquire: invalidate stale caches before reading
}

__global__ __launch_bounds__(256, 2) void mega_kernel(
    float* __restrict__ xbuf, u16* __restrict__ hb, u16* __restrict__ qkvb,
    u16* __restrict__ ob, u16* __restrict__ ub,
    const u16* __restrict__ wqkvt, const u16* __restrict__ wot,
    const u16* __restrict__ w1t, const u16* __restrict__ w2t,
    const float* __restrict__ g1, const float* __restrict__ be1,
    const float* __restrict__ g2, const float* __restrict__ be2,
    const float* __restrict__ gf, const float* __restrict__ bef,
    const float* __restrict__ bo, const float* __restrict__ b1,
    const float* __restrict__ b2, unsigned* bar, int nblk)
{
    __shared__ char smem[65536];
    u16* As = (u16*)smem;
    u16* Bs = (u16*)(smem + BM * KPAD * 2);
    float* ks = (float*)smem;
    float* vs = (float*)(smem + NT * NHS * 4);
    int wid = threadIdx.x >> 6;
    unsigned g = 0;

    for (int l = 0; l < NL; l++) {
        for (int r = blockIdx.x * 4 + wid; r < NBT; r += nblk * 4)
            dev_ln_rows<1>(xbuf, g1 + l * ND, be1 + l * ND, nullptr, hb, r);
        gsync(bar, ++g, nblk);
        for (int t = blockIdx.x; t < (NQKV / BN) * (NBT / BM); t += nblk)
            dev_gemm_tile(hb, wqkvt + (size_t)l * NQKV * ND, nullptr, nullptr, qkvb,
                          NQKV, ND, t / (NQKV / BN), t % (NQKV / BN), FLAG_BF16OUT, As, Bs);
        gsync(bar, ++g, nblk);
        for (int t = blockIdx.x; t < NB * NH; t += nblk)
            dev_attn(qkvb, ob, t, ks, vs);
        gsync(bar, ++g, nblk);
        for (int t = blockIdx.x; t < (ND / BN) * (NBT / BM); t += nblk)
            dev_gemm_tile(ob, wot + (size_t)l * ND * ND, bo + l * ND, xbuf, nullptr,
                          ND, ND, t / (ND / BN), t % (ND / BN), FLAG_BIAS | FLAG_RESID, As, Bs);
        gsync(bar, ++g, nblk);
        for (int r = blockIdx.x * 4 + wid; r < NBT; r += nblk * 4)
            dev_ln_rows<1>(xbuf, g2 + l * ND, be2 + l * ND, nullptr, hb, r);
        gsync(bar, ++g, nblk);
        for (int t = blockIdx.x; t < (NFF / BN) * (NBT / BM); t += nblk)
            dev_gemm_tile(hb, w1t + (size_t)l * ND * NFF, b1 + l * NFF, nullptr, ub,
                          NFF, ND, t / (NFF / BN), t % (NFF / BN),
                          FLAG_BIAS | FLAG_RELU | FLAG_BF16OUT, As, Bs);
        gsync(bar, ++g, nblk);
        for (int t = blockIdx.x; t < (ND / BN) * (NBT / BM); t += nblk)
            dev_gemm_tile(ub, w2t + (size_t)l * NFF * ND, b2 + l * ND, xbuf, nullptr,
                          ND, NFF, t / (ND / BN), t % (ND / BN), FLAG_BIAS | FLAG_RESID, As, Bs);
        gsync(bar, ++g, nblk);
    }
    for (int r = blockIdx.x * 4 + wid; r < NBT; r += nblk * 4)
        dev_ln_rows<1>(xbuf, gf, bef, nullptr, hb, r);
}

// =================== launch ===================

extern "C" void kernel_launch(void* const* d_in, const int* in_sizes, int n_in,
                              void* d_out, int out_size, void* d_ws, size_t ws_size,
                              hipStream_t stream) {
    const int*   tokens  = (const int*)d_in[0];
    const float* tok_emb = (const float*)d_in[1];
    const float* pos_emb = (const float*)d_in[2];
    const float* Wq      = (const float*)d_in[3];
    const float* Wk      = (const float*)d_in[4];
    const float* Wv      = (const float*)d_in[5];
    const float* Wo      = (const float*)d_in[6];
    const float* bo      = (const float*)d_in[7];
    const float* W1      = (const float*)d_in[8];
    const float* b1      = (const float*)d_in[9];
    const float* W2      = (const float*)d_in[10];
    const float* b2      = (const float*)d_in[11];
    const float* g1      = (const float*)d_in[12];
    const float* be1     = (const float*)d_in[13];
    const float* g2      = (const float*)d_in[14];
    const float* be2     = (const float*)d_in[15];
    const float* gf      = (const float*)d_in[16];
    const float* bef     = (const float*)d_in[17];
    const float* Wout    = (const float*)d_in[18];
    const float* bout    = (const float*)d_in[19];
    float* out = (float*)d_out;

    const size_t S_hb   = (size_t)NBT * ND * 2;
    const size_t S_wout = (size_t)NV * ND * 2;
    const size_t S_x    = (size_t)NBT * ND * 4;
    const size_t S_qkv  = (size_t)NBT * NQKV * 2;
    const size_t S_o    = (size_t)NBT * ND * 2;
    const size_t S_u    = (size_t)NBT * NFF * 2;
    const size_t S_wqkv = (size_t)NL * NQKV * ND * 2;
    const size_t S_wo   = (size_t)NL * ND * ND * 2;
    const size_t S_w1   = (size_t)NL * ND * NFF * 2;
    const size_t S_w2   = (size_t)NL * NFF * ND * 2;
    auto al = [](size_t x) { return (x + 255) & ~(size_t)255; };

    const size_t needA = al(S_hb) + al(S_wout) + al(S_x) + al(S_qkv) + al(S_o) +
                         al(S_u) + al(S_wqkv) + al(S_wo) + al(S_w1) + al(S_w2) + 256;
    const size_t needB = al(S_hb) + al(S_wout) + 256;

    char* wsb  = (char*)d_ws;
    char* outb = (char*)d_out;
    bool fp32_logits = false;

    u16 *hb, *woutt, *qkvb, *ob, *ub, *wqkvt, *wot, *w1t, *w2t;
    float *xbuf, *hf = nullptr;
    unsigned* bar = nullptr;

    if (ws_size >= needA) {
        char* p = wsb;
        hb    = (u16*)p; p += al(S_hb);
        woutt = (u16*)p; p += al(S_wout);
        xbuf  = (float*)p; p += al(S_x);
        qkvb  = (u16*)p; p += al(S_qkv);
        ob    = (u16*)p; p += al(S_o);
        ub    = (u16*)p; p += al(S_u);
        wqkvt = (u16*)p; p += al(S_wqkv);
        wot   = (u16*)p; p += al(S_wo);
        w1t   = (u16*)p; p += al(S_w1);
        w2t   = (u16*)p; p += al(S_w2);
        bar   = (unsigned*)p;
    } else if (ws_size >= needB) {
        char* p = wsb;
        hb    = (u16*)p; p += al(S_hb);
        woutt = (u16*)p; p += al(S_wout);
        bar   = (unsigned*)p;
        char* q = outb;
        xbuf  = (float*)q; q += al(S_x);
        qkvb  = (u16*)q; q += al(S_qkv);
        ob    = (u16*)q; q += al(S_o);
        ub    = (u16*)q; q += al(S_u);
        wqkvt = (u16*)q; q += al(S_wqkv);
        wot   = (u16*)q; q += al(S_wo);
        w1t   = (u16*)q; q += al(S_w1);
        w2t   = (u16*)q; q += al(S_w2);
    } else {
        fp32_logits = true;
        hf = (float*)wsb;
        woutt = nullptr;
        char* q = outb;
        hb    = (u16*)q; q += al(S_hb);
        xbuf  = (float*)q; q += al(S_x);
        qkvb  = (u16*)q; q += al(S_qkv);
        ob    = (u16*)q; q += al(S_o);
        ub    = (u16*)q; q += al(S_u);
        wqkvt = (u16*)q; q += al(S_wqkv);
        wot   = (u16*)q; q += al(S_wo);
        w1t   = (u16*)q; q += al(S_w1);
        w2t   = (u16*)q; q += al(S_w2);
    }

    int occ = 0;
    hipOccupancyMaxActiveBlocksPerMultiprocessor(&occ, mega_kernel, 256, 0);
    int nblk = (occ >= 2) ? 512 : (occ == 1 ? 256 : 0);
    bool use_mega = (!fp32_logits) && (nblk > 0) && (bar != nullptr);

    if (use_mega) {
        prep_kernel<<<PREP_GRID, 256, 0, stream>>>(
            tokens, tok_emb, pos_emb, xbuf, Wq, Wk, Wv, Wo, W1, W2, Wout,
            wqkvt, wot, w1t, w2t, woutt);
        hipMemsetAsync(bar, 0, 64, stream);
        mega_kernel<<<nblk, 256, 0, stream>>>(
            xbuf, hb, qkvb, ob, ub, wqkvt, wot, w1t, w2t,
            g1, be1, g2, be2, gf, bef, bo, b1, b2, bar, nblk);
    } else {
        const float* Wsides[3] = {Wq, Wk, Wv};
        for (int s = 0; s < 3; s++)
            transpose_cvt_kernel<<<dim3(NHS / 32, ND / 32, NL * NH), 256, 0, stream>>>(
                Wsides[s], wqkvt + (size_t)s * ND * ND, ND, NHS,
                (long)ND * NHS, (long)NQKV * ND, NH, (long)NHS * ND);
        transpose_cvt_kernel<<<dim3(ND / 32, ND / 32, NL), 256, 0, stream>>>(
            Wo, wot, ND, ND, (long)ND * ND, (long)ND * ND, 1, 0);
        transpose_cvt_kernel<<<dim3(NFF / 32, ND / 32, NL), 256, 0, stream>>>(
            W1, w1t, ND, NFF, (long)ND * NFF, (long)NFF * ND, 1, 0);
        transpose_cvt_kernel<<<dim3(ND / 32, NFF / 32, NL), 256, 0, stream>>>(
            W2, w2t, NFF, ND, (long)NFF * ND, (long)ND * NFF, 1, 0);
        if (!fp32_logits)
            transpose_cvt_kernel<<<dim3(NV / 32, ND / 32, 1), 256, 0, stream>>>(
                Wout, woutt, ND, NV, 0, 0, 1, 0);
        int n = NBT * ND;
        embed_kernel<<<(n + 255) / 256, 256, 0, stream>>>(tokens, tok_emb, pos_emb, xbuf);

        dim3 g_qkv(NQKV / BN, NBT / BM);
        dim3 g_d(ND / BN, NBT / BM);
        dim3 g_ff(NFF / BN, NBT / BM);
        for (int l = 0; l < NL; l++) {
            ln_kernel<1><<<NBT / 4, 256, 0, stream>>>(xbuf, g1 + l * ND, be1 + l * ND, nullptr, hb);
            gemm_bf16_kernel<<<g_qkv, 256, 0, stream>>>(hb, wqkvt + (size_t)l * NQKV * ND,
                nullptr, nullptr, qkvb, NQKV, ND, FLAG_BF16OUT);
            attn_kernel<<<NB * NH, 256, 0, stream>>>(qkvb, ob);
            gemm_bf16_kernel<<<g_d, 256, 0, stream>>>(ob, wot + (size_t)l * ND * ND,
                bo + l * ND, xbuf, nullptr, ND, ND, FLAG_BIAS | FLAG_RESID);
            ln_kernel<1><<<NBT / 4, 256, 0, stream>>>(xbuf, g2 + l * ND, be2 + l * ND, nullptr, hb);
            gemm_bf16_kernel<<<g_ff, 256, 0, stream>>>(hb, w1t + (size_t)l * ND * NFF,
                b1 + l * NFF, nullptr, ub, NFF, ND, FLAG_BIAS | FLAG_RELU | FLAG_BF16OUT);
            gemm_bf16_kernel<<<g_d, 256, 0, stream>>>(ub, w2t + (size_t)l * NFF * ND,
                b2 + l * ND, xbuf, nullptr, ND, NFF, FLAG_BIAS | FLAG_RESID);
        }
        if (!fp32_logits)
            ln_kernel<1><<<NBT / 4, 256, 0, stream>>>(xbuf, gf, bef, nullptr, hb);
        else
            ln_kernel<0><<<NBT / 4, 256, 0, stream>>>(xbuf, gf, bef, hf, nullptr);
    }

    if (!fp32_logits) {
        gemm_bf16_kernel<<<dim3(NV / BN, NBT / BM), 256, 0, stream>>>(
            hb, woutt, bout, out, nullptr, NV, ND, FLAG_BIAS);
    } else {
        gemm_f32_kernel<<<dim3(NV / 64, NBT / 64), 256, 0, stream>>>(
            hf, Wout, bout, out, NBT, NV, ND, 1);
    }
    softmax_kernel<<<NBT, 1024, 0, stream>>>(out);
}